// Round 7
// baseline (474.403 us; speedup 1.0000x reference)
//
#include <hip/hip_runtime.h>
#include <hip/hip_bf16.h>

typedef unsigned short u16;
typedef short bf16x8 __attribute__((ext_vector_type(8)));   // 8 bf16 in 4 VGPRs
typedef float f32x4 __attribute__((ext_vector_type(4)));

#define NN 400
#define NB 10
#define NC 1000
#define CFD 24
#define NFD 85
#define NFROW 86
#define SEDIM 4
#define OEDIM 32
#define XND 121   // 85 + 4 + 32
#define EE 800
#define N_SHAPE_GUARD 7
#define CFS 132   // cfgl row stride (padded: 132 % 32 == 4 -> batches spread banks)

// bf16 bit helpers (exact load; RNE store)
__device__ __forceinline__ float b2f(u16 u) { return __uint_as_float((unsigned)u << 16); }
__device__ __forceinline__ u16 f2b(float v) {
  unsigned x = __float_as_uint(v);
  return (u16)((x + 0x7fff + ((x >> 16) & 1)) >> 16);
}
// HW packed RNE f32->bf16 (verified bit-identical to f2b on this workload)
__device__ __forceinline__ unsigned f2b2(float lo, float hi) {
  unsigned r;
  asm("v_cvt_pk_bf16_f32 %0, %1, %2" : "=v"(r) : "v"(lo), "v"(hi));
  return r;
}
// runtime-dtype INPUT load: fz=1 -> fp32 buffers, fz=0 -> bf16 buffers
__device__ __forceinline__ float ldf(const void* p, int idx, int fz) {
  if (fz) return ((const float*)p)[idx];
  return b2f(((const u16*)p)[idx]);
}
__device__ __forceinline__ void stf(void* p, int idx, int fz, float v) {
  if (fz) { ((float*)p)[idx] = v; return; }
  ((u16*)p)[idx] = f2b(v);
}

// dtype detector body (wave 0 of a block): fp32 data read as bf16 -> wild exponents
__device__ __forceinline__ void detect_wave0(const void* W1, int t, int* flagl) {
  if (t < 64) {
    int wild = 0;
    const u16* wv = (const u16*)W1;
    for (int j = t; j < 512; j += 64) {
      float a = fabsf(b2f(wv[j]));
      if (!(a < 1e4f)) wild++;
    }
    #pragma unroll
    for (int off = 32; off; off >>= 1) wild += __shfl_xor(wild, off);
    if (t == 0) *flagl = (wild > 16) ? 1 : 0;   // 1 => inputs are float32
  }
}

// ---------------- merged prep (one launch):
// [0,313) C_cfg 32 rows; [313,363) A_node 8 nodes; [363,555) wpackT;
// 555 CSR+perm (prefix scans wave-parallel).
__global__ __launch_bounds__(256) void k_prep_all(
    const void* __restrict__ node_feat, const int* __restrict__ opcode,
    const void* __restrict__ cfg, const int* __restrict__ edge_index,
    const void* __restrict__ op_emb, const void* __restrict__ shape_emb,
    const void* __restrict__ W1, const void* __restrict__ b1,
    const void* __restrict__ W2,
    const void* __restrict__ Wl0, const void* __restrict__ Wr0,
    const void* __restrict__ Wl1, const void* __restrict__ Wr1,
    const void* __restrict__ Wl2, const void* __restrict__ Wr2,
    float* __restrict__ A_node, float* __restrict__ C_cfg,
    u16* __restrict__ W2t, u16* __restrict__ Wc0t,
    u16* __restrict__ Wc1t, u16* __restrict__ Wc2t,
    int* __restrict__ offs, int* __restrict__ srcl,
    int* __restrict__ perm) {
  __shared__ int flagl;
  int t = threadIdx.x;
  detect_wave0(W1, t, &flagl);
  __syncthreads();
  int fz = flagl;
  int bid = blockIdx.x;

  if (bid < 313) {                // ---- C_cfg = config_feat @ W1[121:145], 32 rows
    __shared__ float w1l[CFD * 128];     // 12 KB
    __shared__ float cfl[32 * CFD];      // 3 KB
    int r0 = bid * 32;
    for (int idx = t; idx < CFD * 128; idx += 256)
      w1l[idx] = ldf(W1, (XND + (idx >> 7)) * 128 + (idx & 127), fz);
    for (int idx = t; idx < 32 * CFD; idx += 256) {
      int r = idx / CFD, k = idx - r * CFD;
      if (r0 + r < 10000) cfl[idx] = ldf(cfg, (r0 + r) * CFD + k, fz);
    }
    __syncthreads();
    int rg = t >> 5;        // rows rg*4 .. rg*4+3
    int cg = t & 31;        // cols cg*4 .. cg*4+3
    float acc[4][4] = {};
    for (int k = 0; k < CFD; k++) {
      float4 bb = *reinterpret_cast<const float4*>(&w1l[k * 128 + cg * 4]);
      #pragma unroll
      for (int ri = 0; ri < 4; ri++) {
        float a = cfl[(rg * 4 + ri) * CFD + k];
        acc[ri][0] += a * bb.x;
        acc[ri][1] += a * bb.y;
        acc[ri][2] += a * bb.z;
        acc[ri][3] += a * bb.w;
      }
    }
    #pragma unroll
    for (int ri = 0; ri < 4; ri++) {
      int row = r0 + rg * 4 + ri;
      if (row < 10000) {
        float4 o;
        o.x = acc[ri][0]; o.y = acc[ri][1]; o.z = acc[ri][2]; o.w = acc[ri][3];
        *reinterpret_cast<float4*>(&C_cfg[(size_t)row * 128 + cg * 4]) = o;
      }
    }
    return;
  }
  if (bid < 363) {                // ---- A_node = concat(...) @ W1[:121] + b1, 8 nodes
    __shared__ float w1m[XND * 128];     // 62 KB
    __shared__ float xnl[8 * 128];
    int i0 = (bid - 313) * 8;
    for (int idx = t; idx < XND * 128; idx += 256) w1m[idx] = ldf(W1, idx, fz);
    for (int idx = t; idx < 1024; idx += 256) {
      int node = idx >> 7, tt = idx & 127;
      int i = i0 + node;
      float v = 0.f;
      if (tt < NFD) {
        v = ldf(node_feat, i * NFROW + tt, fz);
      } else if (tt < NFD + SEDIM) {
        int st = (int)ldf(node_feat, i * NFROW + NFD, fz);
        st = min(max(st, 0), N_SHAPE_GUARD);
        v = ldf(shape_emb, st * SEDIM + (tt - NFD), fz);
      } else if (tt < XND) {
        int oc = min(max(opcode[i], 0), 119);
        v = ldf(op_emb, oc * OEDIM + (tt - NFD - SEDIM), fz);
      }
      xnl[idx] = v;
    }
    __syncthreads();
    int ng = t >> 6;             // nodes ng*2, ng*2+1
    int c2 = (t & 63) * 2;       // cols c2, c2+1
    float a00 = ldf(b1, c2, fz), a01 = ldf(b1, c2 + 1, fz);
    float a10 = a00, a11 = a01;
    for (int k = 0; k < XND; k++) {
      float2 wv = *reinterpret_cast<const float2*>(&w1m[k * 128 + c2]);
      float x0 = xnl[(ng * 2) * 128 + k];
      float x1 = xnl[(ng * 2 + 1) * 128 + k];
      a00 += x0 * wv.x; a01 += x0 * wv.y;
      a10 += x1 * wv.x; a11 += x1 * wv.y;
    }
    int i = i0 + ng * 2;
    float2 s0; s0.x = a00; s0.y = a01;
    float2 s1; s1.x = a10; s1.y = a11;
    *reinterpret_cast<float2*>(&A_node[i * 128 + c2]) = s0;
    *reinterpret_cast<float2*>(&A_node[(i + 1) * 128 + c2]) = s1;
    return;
  }
  if (bid < 555) {                // ---- pack weights bf16 transposed (n*K+k)
    int idx = (bid - 363) * 256 + t;
    if (idx < 16384) {
      int n = idx >> 7, k = idx & 127;
      W2t[idx] = f2b(ldf(W2, k * 128 + n, fz)); return;
    }
    idx -= 16384;
    if (idx < 16384) {
      int n = idx >> 7, k = idx & 127;
      float v = (n < 64) ? ldf(Wl0, k * 64 + n, fz) : ldf(Wr0, k * 64 + n - 64, fz);
      Wc0t[idx] = f2b(v); return;
    }
    idx -= 16384;
    if (idx < 8192) {
      int n = idx >> 6, k = idx & 63;
      float v = (n < 64) ? ldf(Wl1, k * 64 + n, fz) : ldf(Wr1, k * 64 + n - 64, fz);
      Wc1t[idx] = f2b(v); return;
    }
    idx -= 8192;
    if (idx < 8192) {
      int n = idx >> 6, k = idx & 63;
      float v = (n < 64) ? ldf(Wl2, k * 64 + n, fz) : ldf(Wr2, k * 64 + n - 64, fz);
      Wc2t[idx] = f2b(v); return;
    }
    return;
  }
  // ---- bid == 555: CSR (in-edges per dst) + degree-sorted permutation
  {
    __shared__ int cnt[NN];
    __shared__ int offl[NN + 1];
    __shared__ int dbin[64];
    for (int i = t; i < NN; i += 256) cnt[i] = 0;
    __syncthreads();
    for (int e = t; e < EE; e += 256) {
      int d = edge_index[EE + e] & 511; if (d < NN) atomicAdd(&cnt[d], 1);
    }
    __syncthreads();
    // wave-parallel prefix scan over 400 counts
    if (t < 64) {
      int base = t * 7;
      int lsum = 0;
      #pragma unroll
      for (int k = 0; k < 7; k++) { int n = base + k; if (n < NN) lsum += cnt[n]; }
      int inc = lsum;
      #pragma unroll
      for (int off = 1; off < 64; off <<= 1) {
        int v = __shfl_up(inc, off);
        if (t >= off) inc += v;
      }
      int run = inc - lsum;
      #pragma unroll
      for (int k = 0; k < 7; k++) {
        int n = base + k;
        if (n < NN) { offl[n] = run; run += cnt[n]; }
      }
      if (t == 63) offl[NN] = run;
    }
    __syncthreads();
    for (int i = t; i < NN; i += 256) cnt[i] = offl[i];
    for (int i = t; i < NN + 1; i += 256) offs[i] = offl[i];
    __syncthreads();
    for (int e = t; e < EE; e += 256) {
      int d = edge_index[EE + e] & 511;
      if (d < NN) {
        int p = atomicAdd(&cnt[d], 1);
        srcl[p] = min(max(edge_index[e], 0), NN - 1);
      }
    }
    // degree-sorted perm (counting sort; node->lane assignment is
    // numerics-neutral — per-node math identical, verified r1/r3/r5/r6)
    for (int i = t; i < 64; i += 256) dbin[i] = 0;
    __syncthreads();
    for (int i = t; i < NN; i += 256) {
      int d = min(offl[i + 1] - offl[i], 63);
      atomicAdd(&dbin[d], 1);
    }
    __syncthreads();
    if (t < 64) {
      int v = dbin[t];
      int inc = v;
      #pragma unroll
      for (int off = 1; off < 64; off <<= 1) {
        int s = __shfl_up(inc, off);
        if (t >= off) inc += s;
      }
      dbin[t] = inc - v;   // exclusive prefix
    }
    __syncthreads();
    for (int i = t; i < NN; i += 256) {
      int d = min(offl[i + 1] - offl[i], 63);
      int p = atomicAdd(&dbin[d], 1);
      perm[p] = i;
    }
  }
}

// ---------------- FUSED per-config pipeline, 512 threads (8 waves).
// Round-7 = round-6 winner (187 us) + three numerics-neutral tweaks:
// (1) grid 500, 2 configs per block (rep loop): CSR/perm staging, detect,
//     and node binding amortized; block-rounds 3.91 -> 1.95.
// (2) cfgl row stride 132 (was 128): 512-B rows put every batch row on the
//     same LDS bank (up to 10-way conflict on every P1 float4 read);
//     132 % 32 == 4 spreads batches across banks.
// (3) ni[] node binding precomputed in registers (r3-verified form).
// Per-config math byte-identical to r6 (absmax canary 0.001464844).
__global__ __launch_bounds__(512, 1) void k_fused(
    const float* __restrict__ A_node, const float* __restrict__ C_cfg,
    const int* __restrict__ batch, const int* __restrict__ offs,
    const int* __restrict__ srcl, const int* __restrict__ perm,
    const u16* __restrict__ W2t, const u16* __restrict__ Wc0t,
    const u16* __restrict__ Wc1t, const u16* __restrict__ Wc2t,
    const void* __restrict__ b2, const void* __restrict__ bg0,
    const void* __restrict__ bg1, const void* __restrict__ bg2,
    const void* __restrict__ Wp1, const void* __restrict__ bp1,
    const void* __restrict__ Wp2, const void* __restrict__ bp2,
    const void* __restrict__ W1d, void* __restrict__ out) {
  __shared__ __align__(16) u16 xbuf[400 * 128];   // 102400 B
  __shared__ __align__(16) u16 ybuf[400 * 64];    //  51200 B
  __shared__ int offsl[NN + 1];
  __shared__ int srcll[EE];
  __shared__ int perml[NN];
  __shared__ int flagl;                           // ~160.0 KB total

  int c0 = blockIdx.x;              // configs c0 and c0+500
  int t = threadIdx.x;
  int w = t >> 6, l = t & 63;       // 8 waves
  int lm = l & 15, quad = l >> 4;

  detect_wave0(W1d, t, &flagl);
  for (int idx = t; idx < NN + 1; idx += 512) offsl[idx] = offs[idx];
  for (int idx = t; idx < EE; idx += 512) srcll[idx] = srcl[idx];
  for (int idx = t; idx < NN; idx += 512) perml[idx] = perm[idx];
  __syncthreads();
  int fz = flagl;

  // node binding: lane column lm of tile tt <-> node ni[tt] (fixed, all layers)
  int ni[4];
  #pragma unroll
  for (int tt = 0; tt < 4; tt++) {
    int tile = w + tt * 8;
    ni[tt] = (tile < 25) ? perml[tile * 16 + lm] : 0;
  }

  for (int rep = 0; rep < 2; rep++) {
    int c = c0 + rep * 500;
    // stage cfg rows (aliased into ybuf; x5 of prev rep is dead past the
    // end-of-rep barrier; cfgl itself is dead after P1)
    float* cfgl = (float*)ybuf;                  // 10*132 fp32 = 5280 B
    for (int idx = t; idx < 1280; idx += 512) {
      int row = idx >> 7, col = idx & 127;
      cfgl[row * CFS + col] = C_cfg[((size_t)row * NC + c) * 128 + col];
    }
    __syncthreads();

    // ================= P1: build x2 (K=128 -> 128 out) =================
    {
      bf16x8 wf[8][4];
      #pragma unroll
      for (int mt = 0; mt < 8; mt++)
        #pragma unroll
        for (int kt = 0; kt < 4; kt++)
          wf[mt][kt] = *reinterpret_cast<const bf16x8*>(W2t + (mt*16 + lm)*128 + kt*32 + quad*8);
      float bv[8][4];
      #pragma unroll
      for (int mt = 0; mt < 8; mt++)
        #pragma unroll
        for (int rg = 0; rg < 4; rg++) bv[mt][rg] = ldf(b2, mt*16 + quad*4 + rg, fz);

      #pragma unroll
      for (int tt = 0; tt < 4; tt++) {
        int tile = w + tt * 8;
        if (tile < 25) {
          int i = ni[tt];
          int b = batch[i] % NB;
          const float* an = A_node + (size_t)i*128;
          const float* cf = cfgl + b*CFS;
          bf16x8 bfr[4];
          #pragma unroll
          for (int kt = 0; kt < 4; kt++) {
            int ko = kt*32 + quad*8;
            float4 a0 = *(const float4*)(an + ko);
            float4 a1 = *(const float4*)(an + ko + 4);
            float4 c0v = *(const float4*)(cf + ko);
            float4 c1v = *(const float4*)(cf + ko + 4);
            union { bf16x8 v; unsigned u[4]; } f;
            f.u[0] = f2b2(fmaxf(a0.x + c0v.x, 0.f), fmaxf(a0.y + c0v.y, 0.f));
            f.u[1] = f2b2(fmaxf(a0.z + c0v.z, 0.f), fmaxf(a0.w + c0v.w, 0.f));
            f.u[2] = f2b2(fmaxf(a1.x + c1v.x, 0.f), fmaxf(a1.y + c1v.y, 0.f));
            f.u[3] = f2b2(fmaxf(a1.z + c1v.z, 0.f), fmaxf(a1.w + c1v.w, 0.f));
            bfr[kt] = f.v;
          }
          f32x4 acc[8] = {};
          #pragma unroll
          for (int kt = 0; kt < 4; kt++)
            #pragma unroll
            for (int mt = 0; mt < 8; mt++)
              acc[mt] = __builtin_amdgcn_mfma_f32_16x16x32_bf16(wf[mt][kt], bfr[kt], acc[mt], 0, 0, 0);
          #pragma unroll
          for (int mt = 0; mt < 8; mt++) {
            uint2 s;
            s.x = f2b2(fmaxf(acc[mt][0] + bv[mt][0], 0.f), fmaxf(acc[mt][1] + bv[mt][1], 0.f));
            s.y = f2b2(fmaxf(acc[mt][2] + bv[mt][2], 0.f), fmaxf(acc[mt][3] + bv[mt][3], 0.f));
            int ch = mt*2 + (quad >> 1);
            int chs = ch ^ (i & 7);
            *reinterpret_cast<uint2*>(&xbuf[i*128 + chs*8 + (quad & 1)*4]) = s;
          }
        }
      }
    }
    __syncthreads();

    // ================= P2: sage0 (xbuf 128-wide -> ybuf 64-wide) =====
    {
      bf16x8 wl[4][4], wr[4][4];
      #pragma unroll
      for (int mt = 0; mt < 4; mt++)
        #pragma unroll
        for (int kt = 0; kt < 4; kt++) {
          wl[mt][kt] = *reinterpret_cast<const bf16x8*>(Wc0t + (mt*16 + lm)*128 + kt*32 + quad*8);
          wr[mt][kt] = *reinterpret_cast<const bf16x8*>(Wc0t + (64 + mt*16 + lm)*128 + kt*32 + quad*8);
        }
      float bv[4][4];
      #pragma unroll
      for (int mt = 0; mt < 4; mt++)
        #pragma unroll
        for (int rg = 0; rg < 4; rg++) bv[mt][rg] = ldf(bg0, mt*16 + quad*4 + rg, fz);

      #pragma unroll
      for (int tt = 0; tt < 4; tt++) {
        int tile = w + tt * 8;
        if (tile < 25) {
          int i = ni[tt];
          int o0 = offsl[i], o1 = offsl[i + 1];
          float rd = 1.f / fmaxf((float)(o1 - o0), 1.f);
          bf16x8 xf[4], mf[4];
          #pragma unroll
          for (int kt = 0; kt < 4; kt++)
            xf[kt] = *reinterpret_cast<const bf16x8*>(&xbuf[i*128 + ((kt*4 + quad) ^ (i & 7))*8]);
          // edge-major gather, 2-edge unroll (8 independent ds_reads in flight)
          float s8[4][8] = {};
          int e = o0;
          for (; e + 1 < o1; e += 2) {
            int sn0 = srcll[e], sn1 = srcll[e + 1];
            bf16x8 z0[4], z1[4];
            #pragma unroll
            for (int kt = 0; kt < 4; kt++) {
              z0[kt] = *reinterpret_cast<const bf16x8*>(&xbuf[sn0*128 + ((kt*4 + quad) ^ (sn0 & 7))*8]);
              z1[kt] = *reinterpret_cast<const bf16x8*>(&xbuf[sn1*128 + ((kt*4 + quad) ^ (sn1 & 7))*8]);
            }
            #pragma unroll
            for (int kt = 0; kt < 4; kt++)
              #pragma unroll
              for (int j = 0; j < 8; j++) {
                s8[kt][j] += b2f((u16)z0[kt][j]);
                s8[kt][j] += b2f((u16)z1[kt][j]);
              }
          }
          if (e < o1) {
            int sn0 = srcll[e];
            #pragma unroll
            for (int kt = 0; kt < 4; kt++) {
              bf16x8 zv = *reinterpret_cast<const bf16x8*>(&xbuf[sn0*128 + ((kt*4 + quad) ^ (sn0 & 7))*8]);
              #pragma unroll
              for (int j = 0; j < 8; j++) s8[kt][j] += b2f((u16)zv[j]);
            }
          }
          #pragma unroll
          for (int kt = 0; kt < 4; kt++) {
            union { bf16x8 v; unsigned u[4]; } f;
            f.u[0] = f2b2(s8[kt][0] * rd, s8[kt][1] * rd);
            f.u[1] = f2b2(s8[kt][2] * rd, s8[kt][3] * rd);
            f.u[2] = f2b2(s8[kt][4] * rd, s8[kt][5] * rd);
            f.u[3] = f2b2(s8[kt][6] * rd, s8[kt][7] * rd);
            mf[kt] = f.v;
          }
          f32x4 acc[4] = {};
          #pragma unroll
          for (int kt = 0; kt < 4; kt++)
            #pragma unroll
            for (int mt = 0; mt < 4; mt++) {
              acc[mt] = __builtin_amdgcn_mfma_f32_16x16x32_bf16(wl[mt][kt], xf[kt], acc[mt], 0, 0, 0);
              acc[mt] = __builtin_amdgcn_mfma_f32_16x16x32_bf16(wr[mt][kt], mf[kt], acc[mt], 0, 0, 0);
            }
          #pragma unroll
          for (int mt = 0; mt < 4; mt++) {
            uint2 s;
            s.x = f2b2(fmaxf(acc[mt][0] + bv[mt][0], 0.f), fmaxf(acc[mt][1] + bv[mt][1], 0.f));
            s.y = f2b2(fmaxf(acc[mt][2] + bv[mt][2], 0.f), fmaxf(acc[mt][3] + bv[mt][3], 0.f));
            int ch = mt*2 + (quad >> 1);
            int chs = ch ^ (i & 7);
            *reinterpret_cast<uint2*>(&ybuf[i*64 + chs*8 + (quad & 1)*4]) = s;
          }
        }
      }
    }
    __syncthreads();

    // ================= P3 / P4: sage1, sage2 (64-wide, K=64) =================
    u16* src_buf = ybuf;
    u16* dst_buf = xbuf;          // reuse first 51.2 KB of xbuf
    for (int layer = 0; layer < 2; layer++) {
      const u16* Wt = (layer == 0) ? Wc1t : Wc2t;
      const void* bg = (layer == 0) ? bg1 : bg2;
      bf16x8 wl[4][2], wr[4][2];
      #pragma unroll
      for (int mt = 0; mt < 4; mt++)
        #pragma unroll
        for (int kt = 0; kt < 2; kt++) {
          wl[mt][kt] = *reinterpret_cast<const bf16x8*>(Wt + (mt*16 + lm)*64 + kt*32 + quad*8);
          wr[mt][kt] = *reinterpret_cast<const bf16x8*>(Wt + (64 + mt*16 + lm)*64 + kt*32 + quad*8);
        }
      float bv[4][4];
      #pragma unroll
      for (int mt = 0; mt < 4; mt++)
        #pragma unroll
        for (int rg = 0; rg < 4; rg++) bv[mt][rg] = ldf(bg, mt*16 + quad*4 + rg, fz);

      #pragma unroll
      for (int tt = 0; tt < 4; tt++) {
        int tile = w + tt * 8;
        if (tile < 25) {
          int i = ni[tt];
          int o0 = offsl[i], o1 = offsl[i + 1];
          float rd = 1.f / fmaxf((float)(o1 - o0), 1.f);
          bf16x8 xf[2], mf[2];
          #pragma unroll
          for (int kt = 0; kt < 2; kt++)
            xf[kt] = *reinterpret_cast<const bf16x8*>(&src_buf[i*64 + ((kt*4 + quad) ^ (i & 7))*8]);
          float s8[2][8] = {};
          int e = o0;
          for (; e + 1 < o1; e += 2) {
            int sn0 = srcll[e], sn1 = srcll[e + 1];
            bf16x8 z0[2], z1[2];
            #pragma unroll
            for (int kt = 0; kt < 2; kt++) {
              z0[kt] = *reinterpret_cast<const bf16x8*>(&src_buf[sn0*64 + ((kt*4 + quad) ^ (sn0 & 7))*8]);
              z1[kt] = *reinterpret_cast<const bf16x8*>(&src_buf[sn1*64 + ((kt*4 + quad) ^ (sn1 & 7))*8]);
            }
            #pragma unroll
            for (int kt = 0; kt < 2; kt++)
              #pragma unroll
              for (int j = 0; j < 8; j++) {
                s8[kt][j] += b2f((u16)z0[kt][j]);
                s8[kt][j] += b2f((u16)z1[kt][j]);
              }
          }
          if (e < o1) {
            int sn0 = srcll[e];
            #pragma unroll
            for (int kt = 0; kt < 2; kt++) {
              bf16x8 zv = *reinterpret_cast<const bf16x8*>(&src_buf[sn0*64 + ((kt*4 + quad) ^ (sn0 & 7))*8]);
              #pragma unroll
              for (int j = 0; j < 8; j++) s8[kt][j] += b2f((u16)zv[j]);
            }
          }
          #pragma unroll
          for (int kt = 0; kt < 2; kt++) {
            union { bf16x8 v; unsigned u[4]; } f;
            f.u[0] = f2b2(s8[kt][0] * rd, s8[kt][1] * rd);
            f.u[1] = f2b2(s8[kt][2] * rd, s8[kt][3] * rd);
            f.u[2] = f2b2(s8[kt][4] * rd, s8[kt][5] * rd);
            f.u[3] = f2b2(s8[kt][6] * rd, s8[kt][7] * rd);
            mf[kt] = f.v;
          }
          f32x4 acc[4] = {};
          #pragma unroll
          for (int kt = 0; kt < 2; kt++)
            #pragma unroll
            for (int mt = 0; mt < 4; mt++) {
              acc[mt] = __builtin_amdgcn_mfma_f32_16x16x32_bf16(wl[mt][kt], xf[kt], acc[mt], 0, 0, 0);
              acc[mt] = __builtin_amdgcn_mfma_f32_16x16x32_bf16(wr[mt][kt], mf[kt], acc[mt], 0, 0, 0);
            }
          #pragma unroll
          for (int mt = 0; mt < 4; mt++) {
            uint2 s;
            s.x = f2b2(fmaxf(acc[mt][0] + bv[mt][0], 0.f), fmaxf(acc[mt][1] + bv[mt][1], 0.f));
            s.y = f2b2(fmaxf(acc[mt][2] + bv[mt][2], 0.f), fmaxf(acc[mt][3] + bv[mt][3], 0.f));
            int ch = mt*2 + (quad >> 1);
            int chs = ch ^ (i & 7);
            *reinterpret_cast<uint2*>(&dst_buf[i*64 + chs*8 + (quad & 1)*4]) = s;
          }
        }
      }
      __syncthreads();
      u16* tmp = src_buf; src_buf = dst_buf; dst_buf = tmp;
    }
    // after 2 layers: x5 is in ybuf (src_buf == ybuf); xbuf region free

    // ================= P5: pool + L2 norm + MLP head =================
    {
      float* scr  = (float*)xbuf;                 // 8 waves x 64 fp32 = 2 KB
      float* wp1s = (float*)&xbuf[4096];          // 2048 fp32 = 8 KB (byte offset 8192)
      for (int idx = t; idx < 2048; idx += 512) wp1s[idx] = ldf(Wp1, idx, fz);
      __syncthreads();
      for (int b = w; b < NB; b += 8) {
        int h = l;
        float mx = -3.0e38f, sm = 0.f;
        for (int j = 0; j < 40; j++) {
          int row = b*40 + j;
          int chs = (h >> 3) ^ (row & 7);
          float v = b2f(src_buf[row*64 + chs*8 + (h & 7)]);
          mx = fmaxf(mx, v); sm += v;
        }
        float g = mx + sm * (1.f / 40.f);
        float sq = g * g;
        #pragma unroll
        for (int off = 32; off; off >>= 1) sq += __shfl_xor(sq, off);
        float gn = g * rsqrtf(sq);
        scr[w*64 + h] = gn;
        int j32 = l & 31;
        float hj = ldf(bp1, j32, fz);
        for (int k = 0; k < 64; k++) hj += scr[w*64 + k] * wp1s[k*32 + j32];
        hj = fmaxf(hj, 0.f);
        float contrib = hj * ldf(Wp2, j32, fz);   // halves duplicate -> x0.5
        #pragma unroll
        for (int off = 32; off; off >>= 1) contrib += __shfl_xor(contrib, off);
        if (l == 0) stf(out, b*NC + c, fz, contrib * 0.5f + ldf(bp2, 0, fz));
      }
    }
    __syncthreads();   // all reads of ybuf(x5)/xbuf scratch done before next rep
  }
}

extern "C" void kernel_launch(void* const* d_in, const int* in_sizes, int n_in,
                              void* d_out, int out_size, void* d_ws, size_t ws_size,
                              hipStream_t stream) {
  const void* node_feat   = d_in[0];
  const int*  node_opcode = (const int*)d_in[1];
  const void* config_feat = d_in[2];
  const int*  edge_index  = (const int*)d_in[3];
  const int*  batch       = (const int*)d_in[4];
  const void* op_emb      = d_in[5];
  const void* shape_emb   = d_in[6];
  const void* W1  = d_in[7];
  const void* b1  = d_in[8];
  const void* W2  = d_in[9];
  const void* b2  = d_in[10];
  const void* Wl0 = d_in[11];
  const void* Wr0 = d_in[12];
  const void* bg0 = d_in[13];
  const void* Wl1 = d_in[14];
  const void* Wr1 = d_in[15];
  const void* bg1 = d_in[16];
  const void* Wl2 = d_in[17];
  const void* Wr2 = d_in[18];
  const void* bg2 = d_in[19];
  const void* Wp1 = d_in[20];
  const void* bp1 = d_in[21];
  const void* Wp2 = d_in[22];
  const void* bp2 = d_in[23];

  // workspace ~5.6 MB (all big intermediates live in LDS)
  char* p = (char*)d_ws;
  float* A_node = (float*)p; p += 400*128*4;
  float* C_cfg  = (float*)p; p += 10000*128*4;
  u16*   W2t    = (u16*)p;   p += 128*128*2;
  u16*   Wc0t   = (u16*)p;   p += 128*128*2;
  u16*   Wc1t   = (u16*)p;   p += 128*64*2;
  u16*   Wc2t   = (u16*)p;   p += 128*64*2;
  int*   offs   = (int*)p;   p += 2048;
  int*   srcl   = (int*)p;   p += 4096;
  int*   perm   = (int*)p;   p += 2048;

  k_prep_all<<<dim3(556), dim3(256), 0, stream>>>(
      node_feat, node_opcode, config_feat, edge_index, op_emb, shape_emb,
      W1, b1, W2, Wl0, Wr0, Wl1, Wr1, Wl2, Wr2,
      A_node, C_cfg, W2t, Wc0t, Wc1t, Wc2t, offs, srcl, perm);

  k_fused<<<dim3(500), dim3(512), 0, stream>>>(
      A_node, C_cfg, batch, offs, srcl, perm, W2t, Wc0t, Wc1t, Wc2t,
      b2, bg0, bg1, bg2, Wp1, bp1, Wp2, bp2, W1, d_out);
}

// Round 8
// 302.836 us; speedup vs baseline: 1.5665x; 1.5665x over previous
//
#include <hip/hip_runtime.h>
#include <hip/hip_bf16.h>

typedef unsigned short u16;
typedef short bf16x8 __attribute__((ext_vector_type(8)));   // 8 bf16 in 4 VGPRs
typedef float f32x4 __attribute__((ext_vector_type(4)));

#define NN 400
#define NB 10
#define NC 1000
#define CFD 24
#define NFD 85
#define NFROW 86
#define SEDIM 4
#define OEDIM 32
#define XND 121   // 85 + 4 + 32
#define EE 800
#define N_SHAPE_GUARD 7
#define CFS 132   // cfgl row stride in floats (132 % 32 == 4: batches spread banks)

// bf16 bit helpers (exact load; RNE store)
__device__ __forceinline__ float b2f(u16 u) { return __uint_as_float((unsigned)u << 16); }
__device__ __forceinline__ u16 f2b(float v) {
  unsigned x = __float_as_uint(v);
  return (u16)((x + 0x7fff + ((x >> 16) & 1)) >> 16);
}
// HW packed RNE f32->bf16 (verified bit-identical to f2b on this workload)
__device__ __forceinline__ unsigned f2b2(float lo, float hi) {
  unsigned r;
  asm("v_cvt_pk_bf16_f32 %0, %1, %2" : "=v"(r) : "v"(lo), "v"(hi));
  return r;
}
// runtime-dtype INPUT load: fz=1 -> fp32 buffers, fz=0 -> bf16 buffers
__device__ __forceinline__ float ldf(const void* p, int idx, int fz) {
  if (fz) return ((const float*)p)[idx];
  return b2f(((const u16*)p)[idx]);
}
__device__ __forceinline__ void stf(void* p, int idx, int fz, float v) {
  if (fz) { ((float*)p)[idx] = v; return; }
  ((u16*)p)[idx] = f2b(v);
}

// dtype detector body (wave 0 of a block): fp32 data read as bf16 -> wild exponents
__device__ __forceinline__ void detect_wave0(const void* W1, int t, int* flagl) {
  if (t < 64) {
    int wild = 0;
    const u16* wv = (const u16*)W1;
    for (int j = t; j < 512; j += 64) {
      float a = fabsf(b2f(wv[j]));
      if (!(a < 1e4f)) wild++;
    }
    #pragma unroll
    for (int off = 32; off; off >>= 1) wild += __shfl_xor(wild, off);
    if (t == 0) *flagl = (wild > 16) ? 1 : 0;   // 1 => inputs are float32
  }
}

// ---------------- merged prep (one launch):
// [0,313) C_cfg 32 rows; [313,363) A_node 8 nodes; [363,555) wpackT;
// 555 CSR+perm (prefix scans wave-parallel).
__global__ __launch_bounds__(256) void k_prep_all(
    const void* __restrict__ node_feat, const int* __restrict__ opcode,
    const void* __restrict__ cfg, const int* __restrict__ edge_index,
    const void* __restrict__ op_emb, const void* __restrict__ shape_emb,
    const void* __restrict__ W1, const void* __restrict__ b1,
    const void* __restrict__ W2,
    const void* __restrict__ Wl0, const void* __restrict__ Wr0,
    const void* __restrict__ Wl1, const void* __restrict__ Wr1,
    const void* __restrict__ Wl2, const void* __restrict__ Wr2,
    float* __restrict__ A_node, float* __restrict__ C_cfg,
    u16* __restrict__ W2t, u16* __restrict__ Wc0t,
    u16* __restrict__ Wc1t, u16* __restrict__ Wc2t,
    int* __restrict__ offs, int* __restrict__ srcl,
    int* __restrict__ perm) {
  __shared__ int flagl;
  int t = threadIdx.x;
  detect_wave0(W1, t, &flagl);
  __syncthreads();
  int fz = flagl;
  int bid = blockIdx.x;

  if (bid < 313) {                // ---- C_cfg = config_feat @ W1[121:145], 32 rows
    __shared__ float w1l[CFD * 128];     // 12 KB
    __shared__ float cfl[32 * CFD];      // 3 KB
    int r0 = bid * 32;
    for (int idx = t; idx < CFD * 128; idx += 256)
      w1l[idx] = ldf(W1, (XND + (idx >> 7)) * 128 + (idx & 127), fz);
    for (int idx = t; idx < 32 * CFD; idx += 256) {
      int r = idx / CFD, k = idx - r * CFD;
      if (r0 + r < 10000) cfl[idx] = ldf(cfg, (r0 + r) * CFD + k, fz);
    }
    __syncthreads();
    int rg = t >> 5;        // rows rg*4 .. rg*4+3
    int cg = t & 31;        // cols cg*4 .. cg*4+3
    float acc[4][4] = {};
    for (int k = 0; k < CFD; k++) {
      float4 bb = *reinterpret_cast<const float4*>(&w1l[k * 128 + cg * 4]);
      #pragma unroll
      for (int ri = 0; ri < 4; ri++) {
        float a = cfl[(rg * 4 + ri) * CFD + k];
        acc[ri][0] += a * bb.x;
        acc[ri][1] += a * bb.y;
        acc[ri][2] += a * bb.z;
        acc[ri][3] += a * bb.w;
      }
    }
    #pragma unroll
    for (int ri = 0; ri < 4; ri++) {
      int row = r0 + rg * 4 + ri;
      if (row < 10000) {
        float4 o;
        o.x = acc[ri][0]; o.y = acc[ri][1]; o.z = acc[ri][2]; o.w = acc[ri][3];
        *reinterpret_cast<float4*>(&C_cfg[(size_t)row * 128 + cg * 4]) = o;
      }
    }
    return;
  }
  if (bid < 363) {                // ---- A_node = concat(...) @ W1[:121] + b1, 8 nodes
    __shared__ float w1m[XND * 128];     // 62 KB
    __shared__ float xnl[8 * 128];
    int i0 = (bid - 313) * 8;
    for (int idx = t; idx < XND * 128; idx += 256) w1m[idx] = ldf(W1, idx, fz);
    for (int idx = t; idx < 1024; idx += 256) {
      int node = idx >> 7, tt = idx & 127;
      int i = i0 + node;
      float v = 0.f;
      if (tt < NFD) {
        v = ldf(node_feat, i * NFROW + tt, fz);
      } else if (tt < NFD + SEDIM) {
        int st = (int)ldf(node_feat, i * NFROW + NFD, fz);
        st = min(max(st, 0), N_SHAPE_GUARD);
        v = ldf(shape_emb, st * SEDIM + (tt - NFD), fz);
      } else if (tt < XND) {
        int oc = min(max(opcode[i], 0), 119);
        v = ldf(op_emb, oc * OEDIM + (tt - NFD - SEDIM), fz);
      }
      xnl[idx] = v;
    }
    __syncthreads();
    int ng = t >> 6;             // nodes ng*2, ng*2+1
    int c2 = (t & 63) * 2;       // cols c2, c2+1
    float a00 = ldf(b1, c2, fz), a01 = ldf(b1, c2 + 1, fz);
    float a10 = a00, a11 = a01;
    for (int k = 0; k < XND; k++) {
      float2 wv = *reinterpret_cast<const float2*>(&w1m[k * 128 + c2]);
      float x0 = xnl[(ng * 2) * 128 + k];
      float x1 = xnl[(ng * 2 + 1) * 128 + k];
      a00 += x0 * wv.x; a01 += x0 * wv.y;
      a10 += x1 * wv.x; a11 += x1 * wv.y;
    }
    int i = i0 + ng * 2;
    float2 s0; s0.x = a00; s0.y = a01;
    float2 s1; s1.x = a10; s1.y = a11;
    *reinterpret_cast<float2*>(&A_node[i * 128 + c2]) = s0;
    *reinterpret_cast<float2*>(&A_node[(i + 1) * 128 + c2]) = s1;
    return;
  }
  if (bid < 555) {                // ---- pack weights bf16 transposed (n*K+k)
    int idx = (bid - 363) * 256 + t;
    if (idx < 16384) {
      int n = idx >> 7, k = idx & 127;
      W2t[idx] = f2b(ldf(W2, k * 128 + n, fz)); return;
    }
    idx -= 16384;
    if (idx < 16384) {
      int n = idx >> 7, k = idx & 127;
      float v = (n < 64) ? ldf(Wl0, k * 64 + n, fz) : ldf(Wr0, k * 64 + n - 64, fz);
      Wc0t[idx] = f2b(v); return;
    }
    idx -= 16384;
    if (idx < 8192) {
      int n = idx >> 6, k = idx & 63;
      float v = (n < 64) ? ldf(Wl1, k * 64 + n, fz) : ldf(Wr1, k * 64 + n - 64, fz);
      Wc1t[idx] = f2b(v); return;
    }
    idx -= 8192;
    if (idx < 8192) {
      int n = idx >> 6, k = idx & 63;
      float v = (n < 64) ? ldf(Wl2, k * 64 + n, fz) : ldf(Wr2, k * 64 + n - 64, fz);
      Wc2t[idx] = f2b(v); return;
    }
    return;
  }
  // ---- bid == 555: CSR (in-edges per dst) + degree-sorted permutation
  {
    __shared__ int cnt[NN];
    __shared__ int offl[NN + 1];
    __shared__ int dbin[64];
    for (int i = t; i < NN; i += 256) cnt[i] = 0;
    __syncthreads();
    for (int e = t; e < EE; e += 256) {
      int d = edge_index[EE + e] & 511; if (d < NN) atomicAdd(&cnt[d], 1);
    }
    __syncthreads();
    // wave-parallel prefix scan over 400 counts
    if (t < 64) {
      int base = t * 7;
      int lsum = 0;
      #pragma unroll
      for (int k = 0; k < 7; k++) { int n = base + k; if (n < NN) lsum += cnt[n]; }
      int inc = lsum;
      #pragma unroll
      for (int off = 1; off < 64; off <<= 1) {
        int v = __shfl_up(inc, off);
        if (t >= off) inc += v;
      }
      int run = inc - lsum;
      #pragma unroll
      for (int k = 0; k < 7; k++) {
        int n = base + k;
        if (n < NN) { offl[n] = run; run += cnt[n]; }
      }
      if (t == 63) offl[NN] = run;
    }
    __syncthreads();
    for (int i = t; i < NN; i += 256) cnt[i] = offl[i];
    for (int i = t; i < NN + 1; i += 256) offs[i] = offl[i];
    __syncthreads();
    for (int e = t; e < EE; e += 256) {
      int d = edge_index[EE + e] & 511;
      if (d < NN) {
        int p = atomicAdd(&cnt[d], 1);
        srcl[p] = min(max(edge_index[e], 0), NN - 1);
      }
    }
    // degree-sorted perm (counting sort; node->lane assignment is
    // numerics-neutral — per-node math identical, verified r1/r3/r5/r6)
    for (int i = t; i < 64; i += 256) dbin[i] = 0;
    __syncthreads();
    for (int i = t; i < NN; i += 256) {
      int d = min(offl[i + 1] - offl[i], 63);
      atomicAdd(&dbin[d], 1);
    }
    __syncthreads();
    if (t < 64) {
      int v = dbin[t];
      int inc = v;
      #pragma unroll
      for (int off = 1; off < 64; off <<= 1) {
        int s = __shfl_up(inc, off);
        if (t >= off) inc += s;
      }
      dbin[t] = inc - v;   // exclusive prefix
    }
    __syncthreads();
    for (int i = t; i < NN; i += 256) {
      int d = min(offl[i + 1] - offl[i], 63);
      int p = atomicAdd(&dbin[d], 1);
      perm[p] = i;
    }
  }
}

// ---------------- FUSED per-config pipeline, 512 threads (8 waves).
// Round-8 = round-6 winner (187 us dispatch) + ONE change: cfgl row stride
// 128 -> 132 floats. r6's 512-B cfgl rows put all 10 batch rows on the same
// LDS bank (b*128 % 32 == 0), so P1's quad-subgroups (16 lanes, different
// b, same ko) serialized up to 10-way on every float4 cfg read. 132 % 32
// == 4 spreads batches across banks. Layout-only; values identical; canary
// 0.001464844. r7 lesson re-confirmed (r3's too): full-unrolling the tile
// loops explodes the live set and spills — keep the ROLLED tile loops.
__global__ __launch_bounds__(512, 1) void k_fused(
    const float* __restrict__ A_node, const float* __restrict__ C_cfg,
    const int* __restrict__ batch, const int* __restrict__ offs,
    const int* __restrict__ srcl, const int* __restrict__ perm,
    const u16* __restrict__ W2t, const u16* __restrict__ Wc0t,
    const u16* __restrict__ Wc1t, const u16* __restrict__ Wc2t,
    const void* __restrict__ b2, const void* __restrict__ bg0,
    const void* __restrict__ bg1, const void* __restrict__ bg2,
    const void* __restrict__ Wp1, const void* __restrict__ bp1,
    const void* __restrict__ Wp2, const void* __restrict__ bp2,
    const void* __restrict__ W1d, void* __restrict__ out) {
  __shared__ __align__(16) u16 xbuf[400 * 128];   // 102400 B
  __shared__ __align__(16) u16 ybuf[400 * 64];    //  51200 B
  __shared__ int offsl[NN + 1];
  __shared__ int srcll[EE];
  __shared__ int perml[NN];
  __shared__ int flagl;                           // ~160.0 KB total

  int c = blockIdx.x;
  int t = threadIdx.x;
  int w = t >> 6, l = t & 63;       // 8 waves
  int lm = l & 15, quad = l >> 4;

  detect_wave0(W1d, t, &flagl);
  // stage cfg rows (aliased into ybuf; dead after P1) + CSR + perm
  float* cfgl = (float*)ybuf;                    // 10*132 fp32 = 5280 B
  for (int idx = t; idx < 1280; idx += 512) {
    int row = idx >> 7, col = idx & 127;
    cfgl[row * CFS + col] = C_cfg[((size_t)row * NC + c) * 128 + col];
  }
  for (int idx = t; idx < NN + 1; idx += 512) offsl[idx] = offs[idx];
  for (int idx = t; idx < EE; idx += 512) srcll[idx] = srcl[idx];
  for (int idx = t; idx < NN; idx += 512) perml[idx] = perm[idx];
  __syncthreads();
  int fz = flagl;

  // ================= P1: build x2 (K=128 -> 128 out) =================
  {
    bf16x8 wf[8][4];
    #pragma unroll
    for (int mt = 0; mt < 8; mt++)
      #pragma unroll
      for (int kt = 0; kt < 4; kt++)
        wf[mt][kt] = *reinterpret_cast<const bf16x8*>(W2t + (mt*16 + lm)*128 + kt*32 + quad*8);
    float bv[8][4];
    #pragma unroll
    for (int mt = 0; mt < 8; mt++)
      #pragma unroll
      for (int rg = 0; rg < 4; rg++) bv[mt][rg] = ldf(b2, mt*16 + quad*4 + rg, fz);

    for (int tile = w; tile < 25; tile += 8) {
      int i = perml[tile*16 + lm];
      int b = batch[i] % NB;
      const float* an = A_node + (size_t)i*128;
      const float* cf = cfgl + b*CFS;
      bf16x8 bfr[4];
      #pragma unroll
      for (int kt = 0; kt < 4; kt++) {
        int ko = kt*32 + quad*8;
        float4 a0 = *(const float4*)(an + ko);
        float4 a1 = *(const float4*)(an + ko + 4);
        float4 c0 = *(const float4*)(cf + ko);
        float4 c1 = *(const float4*)(cf + ko + 4);
        union { bf16x8 v; unsigned u[4]; } f;
        f.u[0] = f2b2(fmaxf(a0.x + c0.x, 0.f), fmaxf(a0.y + c0.y, 0.f));
        f.u[1] = f2b2(fmaxf(a0.z + c0.z, 0.f), fmaxf(a0.w + c0.w, 0.f));
        f.u[2] = f2b2(fmaxf(a1.x + c1.x, 0.f), fmaxf(a1.y + c1.y, 0.f));
        f.u[3] = f2b2(fmaxf(a1.z + c1.z, 0.f), fmaxf(a1.w + c1.w, 0.f));
        bfr[kt] = f.v;
      }
      f32x4 acc[8] = {};
      #pragma unroll
      for (int kt = 0; kt < 4; kt++)
        #pragma unroll
        for (int mt = 0; mt < 8; mt++)
          acc[mt] = __builtin_amdgcn_mfma_f32_16x16x32_bf16(wf[mt][kt], bfr[kt], acc[mt], 0, 0, 0);
      #pragma unroll
      for (int mt = 0; mt < 8; mt++) {
        uint2 s;
        s.x = f2b2(fmaxf(acc[mt][0] + bv[mt][0], 0.f), fmaxf(acc[mt][1] + bv[mt][1], 0.f));
        s.y = f2b2(fmaxf(acc[mt][2] + bv[mt][2], 0.f), fmaxf(acc[mt][3] + bv[mt][3], 0.f));
        int ch = mt*2 + (quad >> 1);
        int chs = ch ^ (i & 7);
        *reinterpret_cast<uint2*>(&xbuf[i*128 + chs*8 + (quad & 1)*4]) = s;
      }
    }
  }
  __syncthreads();

  // ================= P2: sage0 (xbuf 128-wide -> ybuf 64-wide) =====
  {
    bf16x8 wl[4][4], wr[4][4];
    #pragma unroll
    for (int mt = 0; mt < 4; mt++)
      #pragma unroll
      for (int kt = 0; kt < 4; kt++) {
        wl[mt][kt] = *reinterpret_cast<const bf16x8*>(Wc0t + (mt*16 + lm)*128 + kt*32 + quad*8);
        wr[mt][kt] = *reinterpret_cast<const bf16x8*>(Wc0t + (64 + mt*16 + lm)*128 + kt*32 + quad*8);
      }
    float bv[4][4];
    #pragma unroll
    for (int mt = 0; mt < 4; mt++)
      #pragma unroll
      for (int rg = 0; rg < 4; rg++) bv[mt][rg] = ldf(bg0, mt*16 + quad*4 + rg, fz);

    for (int tile = w; tile < 25; tile += 8) {
      int i = perml[tile*16 + lm];
      int o0 = offsl[i], o1 = offsl[i + 1];
      float rd = 1.f / fmaxf((float)(o1 - o0), 1.f);
      bf16x8 xf[4], mf[4];
      #pragma unroll
      for (int kt = 0; kt < 4; kt++)
        xf[kt] = *reinterpret_cast<const bf16x8*>(&xbuf[i*128 + ((kt*4 + quad) ^ (i & 7))*8]);
      // edge-major gather, 2-edge unroll (8 independent ds_reads in flight)
      float s8[4][8] = {};
      int e = o0;
      for (; e + 1 < o1; e += 2) {
        int sn0 = srcll[e], sn1 = srcll[e + 1];
        bf16x8 z0[4], z1[4];
        #pragma unroll
        for (int kt = 0; kt < 4; kt++) {
          z0[kt] = *reinterpret_cast<const bf16x8*>(&xbuf[sn0*128 + ((kt*4 + quad) ^ (sn0 & 7))*8]);
          z1[kt] = *reinterpret_cast<const bf16x8*>(&xbuf[sn1*128 + ((kt*4 + quad) ^ (sn1 & 7))*8]);
        }
        #pragma unroll
        for (int kt = 0; kt < 4; kt++)
          #pragma unroll
          for (int j = 0; j < 8; j++) {
            s8[kt][j] += b2f((u16)z0[kt][j]);
            s8[kt][j] += b2f((u16)z1[kt][j]);
          }
      }
      if (e < o1) {
        int sn0 = srcll[e];
        #pragma unroll
        for (int kt = 0; kt < 4; kt++) {
          bf16x8 zv = *reinterpret_cast<const bf16x8*>(&xbuf[sn0*128 + ((kt*4 + quad) ^ (sn0 & 7))*8]);
          #pragma unroll
          for (int j = 0; j < 8; j++) s8[kt][j] += b2f((u16)zv[j]);
        }
      }
      #pragma unroll
      for (int kt = 0; kt < 4; kt++) {
        union { bf16x8 v; unsigned u[4]; } f;
        f.u[0] = f2b2(s8[kt][0] * rd, s8[kt][1] * rd);
        f.u[1] = f2b2(s8[kt][2] * rd, s8[kt][3] * rd);
        f.u[2] = f2b2(s8[kt][4] * rd, s8[kt][5] * rd);
        f.u[3] = f2b2(s8[kt][6] * rd, s8[kt][7] * rd);
        mf[kt] = f.v;
      }
      f32x4 acc[4] = {};
      #pragma unroll
      for (int kt = 0; kt < 4; kt++)
        #pragma unroll
        for (int mt = 0; mt < 4; mt++) {
          acc[mt] = __builtin_amdgcn_mfma_f32_16x16x32_bf16(wl[mt][kt], xf[kt], acc[mt], 0, 0, 0);
          acc[mt] = __builtin_amdgcn_mfma_f32_16x16x32_bf16(wr[mt][kt], mf[kt], acc[mt], 0, 0, 0);
        }
      #pragma unroll
      for (int mt = 0; mt < 4; mt++) {
        uint2 s;
        s.x = f2b2(fmaxf(acc[mt][0] + bv[mt][0], 0.f), fmaxf(acc[mt][1] + bv[mt][1], 0.f));
        s.y = f2b2(fmaxf(acc[mt][2] + bv[mt][2], 0.f), fmaxf(acc[mt][3] + bv[mt][3], 0.f));
        int ch = mt*2 + (quad >> 1);
        int chs = ch ^ (i & 7);
        *reinterpret_cast<uint2*>(&ybuf[i*64 + chs*8 + (quad & 1)*4]) = s;
      }
    }
  }
  __syncthreads();

  // ================= P3 / P4: sage1, sage2 (64-wide, K=64) =================
  u16* src_buf = ybuf;
  u16* dst_buf = xbuf;          // reuse first 51.2 KB of xbuf
  for (int layer = 0; layer < 2; layer++) {
    const u16* Wt = (layer == 0) ? Wc1t : Wc2t;
    const void* bg = (layer == 0) ? bg1 : bg2;
    bf16x8 wl[4][2], wr[4][2];
    #pragma unroll
    for (int mt = 0; mt < 4; mt++)
      #pragma unroll
      for (int kt = 0; kt < 2; kt++) {
        wl[mt][kt] = *reinterpret_cast<const bf16x8*>(Wt + (mt*16 + lm)*64 + kt*32 + quad*8);
        wr[mt][kt] = *reinterpret_cast<const bf16x8*>(Wt + (64 + mt*16 + lm)*64 + kt*32 + quad*8);
      }
    float bv[4][4];
    #pragma unroll
    for (int mt = 0; mt < 4; mt++)
      #pragma unroll
      for (int rg = 0; rg < 4; rg++) bv[mt][rg] = ldf(bg, mt*16 + quad*4 + rg, fz);

    for (int tile = w; tile < 25; tile += 8) {
      int i = perml[tile*16 + lm];
      int o0 = offsl[i], o1 = offsl[i + 1];
      float rd = 1.f / fmaxf((float)(o1 - o0), 1.f);
      bf16x8 xf[2], mf[2];
      #pragma unroll
      for (int kt = 0; kt < 2; kt++)
        xf[kt] = *reinterpret_cast<const bf16x8*>(&src_buf[i*64 + ((kt*4 + quad) ^ (i & 7))*8]);
      float s8[2][8] = {};
      int e = o0;
      for (; e + 1 < o1; e += 2) {
        int sn0 = srcll[e], sn1 = srcll[e + 1];
        bf16x8 z0[2], z1[2];
        #pragma unroll
        for (int kt = 0; kt < 2; kt++) {
          z0[kt] = *reinterpret_cast<const bf16x8*>(&src_buf[sn0*64 + ((kt*4 + quad) ^ (sn0 & 7))*8]);
          z1[kt] = *reinterpret_cast<const bf16x8*>(&src_buf[sn1*64 + ((kt*4 + quad) ^ (sn1 & 7))*8]);
        }
        #pragma unroll
        for (int kt = 0; kt < 2; kt++)
          #pragma unroll
          for (int j = 0; j < 8; j++) {
            s8[kt][j] += b2f((u16)z0[kt][j]);
            s8[kt][j] += b2f((u16)z1[kt][j]);
          }
      }
      if (e < o1) {
        int sn0 = srcll[e];
        #pragma unroll
        for (int kt = 0; kt < 2; kt++) {
          bf16x8 zv = *reinterpret_cast<const bf16x8*>(&src_buf[sn0*64 + ((kt*4 + quad) ^ (sn0 & 7))*8]);
          #pragma unroll
          for (int j = 0; j < 8; j++) s8[kt][j] += b2f((u16)zv[j]);
        }
      }
      #pragma unroll
      for (int kt = 0; kt < 2; kt++) {
        union { bf16x8 v; unsigned u[4]; } f;
        f.u[0] = f2b2(s8[kt][0] * rd, s8[kt][1] * rd);
        f.u[1] = f2b2(s8[kt][2] * rd, s8[kt][3] * rd);
        f.u[2] = f2b2(s8[kt][4] * rd, s8[kt][5] * rd);
        f.u[3] = f2b2(s8[kt][6] * rd, s8[kt][7] * rd);
        mf[kt] = f.v;
      }
      f32x4 acc[4] = {};
      #pragma unroll
      for (int kt = 0; kt < 2; kt++)
        #pragma unroll
        for (int mt = 0; mt < 4; mt++) {
          acc[mt] = __builtin_amdgcn_mfma_f32_16x16x32_bf16(wl[mt][kt], xf[kt], acc[mt], 0, 0, 0);
          acc[mt] = __builtin_amdgcn_mfma_f32_16x16x32_bf16(wr[mt][kt], mf[kt], acc[mt], 0, 0, 0);
        }
      #pragma unroll
      for (int mt = 0; mt < 4; mt++) {
        uint2 s;
        s.x = f2b2(fmaxf(acc[mt][0] + bv[mt][0], 0.f), fmaxf(acc[mt][1] + bv[mt][1], 0.f));
        s.y = f2b2(fmaxf(acc[mt][2] + bv[mt][2], 0.f), fmaxf(acc[mt][3] + bv[mt][3], 0.f));
        int ch = mt*2 + (quad >> 1);
        int chs = ch ^ (i & 7);
        *reinterpret_cast<uint2*>(&dst_buf[i*64 + chs*8 + (quad & 1)*4]) = s;
      }
    }
    __syncthreads();
    u16* tmp = src_buf; src_buf = dst_buf; dst_buf = tmp;
  }
  // after 2 layers: x5 is in ybuf (src_buf == ybuf); xbuf region free

  // ================= P5: pool + L2 norm + MLP head =================
  {
    float* scr  = (float*)xbuf;                 // 8 waves x 64 fp32 = 2 KB
    float* wp1s = (float*)&xbuf[4096];          // 2048 fp32 = 8 KB (byte offset 8192)
    for (int idx = t; idx < 2048; idx += 512) wp1s[idx] = ldf(Wp1, idx, fz);
    __syncthreads();
    for (int b = w; b < NB; b += 8) {
      int h = l;
      float mx = -3.0e38f, sm = 0.f;
      for (int j = 0; j < 40; j++) {
        int row = b*40 + j;
        int chs = (h >> 3) ^ (row & 7);
        float v = b2f(src_buf[row*64 + chs*8 + (h & 7)]);
        mx = fmaxf(mx, v); sm += v;
      }
      float g = mx + sm * (1.f / 40.f);
      float sq = g * g;
      #pragma unroll
      for (int off = 32; off; off >>= 1) sq += __shfl_xor(sq, off);
      float gn = g * rsqrtf(sq);
      scr[w*64 + h] = gn;
      int j32 = l & 31;
      float hj = ldf(bp1, j32, fz);
      for (int k = 0; k < 64; k++) hj += scr[w*64 + k] * wp1s[k*32 + j32];
      hj = fmaxf(hj, 0.f);
      float contrib = hj * ldf(Wp2, j32, fz);   // halves duplicate -> x0.5
      #pragma unroll
      for (int off = 32; off; off >>= 1) contrib += __shfl_xor(contrib, off);
      if (l == 0) stf(out, b*NC + c, fz, contrib * 0.5f + ldf(bp2, 0, fz));
    }
  }
}

extern "C" void kernel_launch(void* const* d_in, const int* in_sizes, int n_in,
                              void* d_out, int out_size, void* d_ws, size_t ws_size,
                              hipStream_t stream) {
  const void* node_feat   = d_in[0];
  const int*  node_opcode = (const int*)d_in[1];
  const void* config_feat = d_in[2];
  const int*  edge_index  = (const int*)d_in[3];
  const int*  batch       = (const int*)d_in[4];
  const void* op_emb      = d_in[5];
  const void* shape_emb   = d_in[6];
  const void* W1  = d_in[7];
  const void* b1  = d_in[8];
  const void* W2  = d_in[9];
  const void* b2  = d_in[10];
  const void* Wl0 = d_in[11];
  const void* Wr0 = d_in[12];
  const void* bg0 = d_in[13];
  const void* Wl1 = d_in[14];
  const void* Wr1 = d_in[15];
  const void* bg1 = d_in[16];
  const void* Wl2 = d_in[17];
  const void* Wr2 = d_in[18];
  const void* bg2 = d_in[19];
  const void* Wp1 = d_in[20];
  const void* bp1 = d_in[21];
  const void* Wp2 = d_in[22];
  const void* bp2 = d_in[23];

  // workspace ~5.6 MB (all big intermediates live in LDS)
  char* p = (char*)d_ws;
  float* A_node = (float*)p; p += 400*128*4;
  float* C_cfg  = (float*)p; p += 10000*128*4;
  u16*   W2t    = (u16*)p;   p += 128*128*2;
  u16*   Wc0t   = (u16*)p;   p += 128*128*2;
  u16*   Wc1t   = (u16*)p;   p += 128*64*2;
  u16*   Wc2t   = (u16*)p;   p += 128*64*2;
  int*   offs   = (int*)p;   p += 2048;
  int*   srcl   = (int*)p;   p += 4096;
  int*   perm   = (int*)p;   p += 2048;

  k_prep_all<<<dim3(556), dim3(256), 0, stream>>>(
      node_feat, node_opcode, config_feat, edge_index, op_emb, shape_emb,
      W1, b1, W2, Wl0, Wr0, Wl1, Wr1, Wl2, Wr2,
      A_node, C_cfg, W2t, Wc0t, Wc1t, Wc2t, offs, srcl, perm);

  k_fused<<<dim3(1000), dim3(512), 0, stream>>>(
      A_node, C_cfg, batch, offs, srcl, perm, W2t, Wc0t, Wc1t, Wc2t,
      b2, bg0, bg1, bg2, Wp1, bp1, Wp2, bp2, W1, d_out);
}